// Round 1
// baseline (226.892 us; speedup 1.0000x reference)
//
#include <hip/hip_runtime.h>
#include <hip/hip_bf16.h>
#include <math.h>

#define NB 512
#define NS 200
#define NH 256
#define TILE_S 32
#define NTILES ((NS + TILE_S - 1) / TILE_S)   // 7
#define LDSPAD 8
#define LDW (NH + LDSPAD)                     // 264 bf16 row stride -> breaks pow2 banking

typedef __bf16 bf16x8 __attribute__((ext_vector_type(8)));
typedef float  f32x4  __attribute__((ext_vector_type(4)));

__device__ __forceinline__ float tanh_fast(float x) {
  // tanh(x) = (e^{2x}-1)/(e^{2x}+1); clamp so __expf never overflows
  float xc = fminf(fmaxf(x, -10.f), 10.f);
  float e  = __expf(2.f * xc);
  return (e - 1.f) / (e + 1.f);
}

__global__ __launch_bounds__(256, 2)
void fused_meta_attn(const float* __restrict__ mem,    // [B,S,H]
                     const float* __restrict__ lastm,  // [B,H]
                     const float* __restrict__ U,      // [H,H]
                     const float* __restrict__ W,      // [H,H]
                     const float* __restrict__ V,      // [H,1] -> [H]
                     const float* __restrict__ MetaW,  // [4,H]
                     const float* __restrict__ Metab,  // [4]
                     float* __restrict__ out)          // [B,4]
{
  const int b    = blockIdx.x;
  const int t    = threadIdx.x;   // 0..255
  const int wave = t >> 6;        // 0..3 -> owns output cols [wave*64, wave*64+64)
  const int lane = t & 63;
  const int m16  = lane & 15;
  const int quad = lane >> 4;

  __shared__ __align__(16) __bf16 mem_sm[TILE_S][LDW];  // 16.9 KB
  __shared__ float lm_sm[NH];
  __shared__ float l_sm[NH];
  __shared__ float v_sm[NH];
  __shared__ float swave_sm[4][TILE_S];
  __shared__ float scores_sm[TILE_S];
  __shared__ float pooled_sm[NH];

  lm_sm[t] = lastm[(size_t)b * NH + t];
  v_sm[t]  = V[t];
  __syncthreads();

  // ---- l[t] = dot(lastm[b,:], W[t,:])  (fp32, exact) ----
  {
    const float4* wrow = (const float4*)(W + (size_t)t * NH);
    const float4* lrow = (const float4*)lm_sm;
    float a0 = 0.f, a1 = 0.f, a2 = 0.f, a3 = 0.f;
#pragma unroll 8
    for (int i = 0; i < NH / 4; ++i) {
      float4 w4 = wrow[i];
      float4 m4 = lrow[i];
      a0 = fmaf(w4.x, m4.x, a0);
      a1 = fmaf(w4.y, m4.y, a1);
      a2 = fmaf(w4.z, m4.z, a2);
      a3 = fmaf(w4.w, m4.w, a3);
    }
    l_sm[t] = (a0 + a1) + (a2 + a3);
  }

  // ---- U B-fragments into registers, held for whole kernel ----
  // B[k=h][n] lane map: n = n0 + m16, k = kk*32 + quad*8 + j  (U row-major = B^T)
  bf16x8 u_frag[4][8];
#pragma unroll
  for (int nf = 0; nf < 4; ++nf) {
    const int n = wave * 64 + nf * 16 + m16;
    const float* urow = U + (size_t)n * NH;
#pragma unroll
    for (int kk = 0; kk < 8; ++kk) {
      const float4 lo = *(const float4*)(urow + kk * 32 + quad * 8);
      const float4 hi = *(const float4*)(urow + kk * 32 + quad * 8 + 4);
      bf16x8 f;
      f[0] = (__bf16)lo.x; f[1] = (__bf16)lo.y;
      f[2] = (__bf16)lo.z; f[3] = (__bf16)lo.w;
      f[4] = (__bf16)hi.x; f[5] = (__bf16)hi.y;
      f[6] = (__bf16)hi.z; f[7] = (__bf16)hi.w;
      u_frag[nf][kk] = f;
    }
  }

  float m_run  = -INFINITY;
  float Z      = 0.f;
  float pooled = 0.f;   // thread t owns h = t

  __syncthreads();      // l_sm ready

  float l_reg[4], v_reg[4];
#pragma unroll
  for (int nf = 0; nf < 4; ++nf) {
    const int n = wave * 64 + nf * 16 + m16;
    l_reg[nf] = l_sm[n];
    v_reg[nf] = v_sm[n];
  }

  for (int tile = 0; tile < NTILES; ++tile) {
    const int s0   = tile * TILE_S;
    const int rows = min(TILE_S, NS - s0);

    // ---- stage s-tile fp32 -> bf16 LDS (coalesced float4, zero-pad OOB rows) ----
    const float4* src = (const float4*)(mem + ((size_t)b * NS + s0) * NH);
#pragma unroll
    for (int i = 0; i < (TILE_S * NH / 4) / 256; ++i) {   // 8 iters
      const int f   = i * 256 + t;
      const int row = f >> 6;
      const int c4  = (f & 63) * 4;
      float4 v4;
      if (row < rows) v4 = src[f];
      else            v4 = make_float4(0.f, 0.f, 0.f, 0.f);
      __bf16* dst = &mem_sm[row][c4];
      dst[0] = (__bf16)v4.x; dst[1] = (__bf16)v4.y;
      dst[2] = (__bf16)v4.z; dst[3] = (__bf16)v4.w;
    }
    __syncthreads();

    // ---- MFMA: a[s, n] for 32 rows x 64 cols per wave ----
    f32x4 acc[2][4];
    const f32x4 fzero = {0.f, 0.f, 0.f, 0.f};
#pragma unroll
    for (int mt = 0; mt < 2; ++mt)
#pragma unroll
      for (int nf = 0; nf < 4; ++nf)
        acc[mt][nf] = fzero;

#pragma unroll
    for (int kk = 0; kk < 8; ++kk) {
      const int c = kk * 32 + quad * 8;
      bf16x8 a0 = *(const bf16x8*)&mem_sm[m16][c];
      bf16x8 a1 = *(const bf16x8*)&mem_sm[16 + m16][c];
#pragma unroll
      for (int nf = 0; nf < 4; ++nf) {
        acc[0][nf] = __builtin_amdgcn_mfma_f32_16x16x32_bf16(a0, u_frag[nf][kk], acc[0][nf], 0, 0, 0);
        acc[1][nf] = __builtin_amdgcn_mfma_f32_16x16x32_bf16(a1, u_frag[nf][kk], acc[1][nf], 0, 0, 0);
      }
    }

    // ---- epilogue: p = sum_n tanh(a + l[n]) * V[n] over this wave's 64 n ----
    // C/D layout: value reg of frag (mt,nf): row = mt*16 + quad*4 + reg, col n = nf*16 + m16
    float p[2][4];
#pragma unroll
    for (int mt = 0; mt < 2; ++mt) {
#pragma unroll
      for (int reg = 0; reg < 4; ++reg) {
        float s = 0.f;
#pragma unroll
        for (int nf = 0; nf < 4; ++nf)
          s = fmaf(tanh_fast(acc[mt][nf][reg] + l_reg[nf]), v_reg[nf], s);
        p[mt][reg] = s;
      }
    }
    // reduce across the 16 lanes of each quad (the n-minor dim)
#pragma unroll
    for (int off = 1; off < 16; off <<= 1) {
#pragma unroll
      for (int mt = 0; mt < 2; ++mt)
#pragma unroll
        for (int reg = 0; reg < 4; ++reg)
          p[mt][reg] += __shfl_xor(p[mt][reg], off);
    }
    if (m16 == 0) {
#pragma unroll
      for (int mt = 0; mt < 2; ++mt)
#pragma unroll
        for (int reg = 0; reg < 4; ++reg)
          swave_sm[wave][mt * 16 + quad * 4 + reg] = p[mt][reg];
    }
    __syncthreads();

    if (t < TILE_S)
      scores_sm[t] = swave_sm[0][t] + swave_sm[1][t] + swave_sm[2][t] + swave_sm[3][t];
    __syncthreads();

    // ---- online softmax + pooling update (thread t owns h=t; all threads
    //      compute identical m/Z deterministically from the same LDS data) ----
    float m_tile = -INFINITY;
    for (int r = 0; r < rows; ++r) m_tile = fmaxf(m_tile, scores_sm[r]);
    const float m_new = fmaxf(m_run, m_tile);
    const float fac   = __expf(m_run - m_new);   // exp(-inf)=0 on first tile
    float z_t = 0.f, pool_t = 0.f;
    for (int r = 0; r < rows; ++r) {
      const float e = __expf(scores_sm[r] - m_new);
      z_t += e;
      pool_t = fmaf(e, (float)mem_sm[r][t], pool_t);
    }
    Z      = Z * fac + z_t;
    pooled = pooled * fac + pool_t;
    m_run  = m_new;
    __syncthreads();   // before next tile overwrites mem_sm/swave/scores
  }

  pooled_sm[t] = pooled / Z;
  __syncthreads();

  // ---- out[b, j] = pooled . MetaW[j,:] + Metab[j]; wave w computes j=w ----
  float s = 0.f;
#pragma unroll
  for (int i = 0; i < 4; ++i) {
    const int h = i * 64 + lane;
    s = fmaf(pooled_sm[h], MetaW[(size_t)wave * NH + h], s);
  }
#pragma unroll
  for (int off = 32; off > 0; off >>= 1)
    s += __shfl_down(s, off);
  if (lane == 0)
    out[b * 4 + wave] = s + Metab[wave];
}

extern "C" void kernel_launch(void* const* d_in, const int* in_sizes, int n_in,
                              void* d_out, int out_size, void* d_ws, size_t ws_size,
                              hipStream_t stream) {
  const float* mem   = (const float*)d_in[0];
  const float* lastm = (const float*)d_in[1];
  const float* U     = (const float*)d_in[2];
  const float* W     = (const float*)d_in[3];
  const float* V     = (const float*)d_in[4];
  const float* MetaW = (const float*)d_in[5];
  const float* Metab = (const float*)d_in[6];
  float* out = (float*)d_out;

  hipLaunchKernelGGL(fused_meta_attn, dim3(NB), dim3(256), 0, stream,
                     mem, lastm, U, W, V, MetaW, Metab, out);
}